// Round 5
// baseline (691.245 us; speedup 1.0000x reference)
//
#include <hip/hip_runtime.h>
#include <hip/hip_bf16.h>
#include <stdint.h>

#define B_   2
#define T_   2048
#define H_   2048
#define NH_  16
#define NKV_ 4
#define HD_  128
#define M_   (B_*T_)
#define SCALE_ 0.08838834764831845f

typedef __hip_bfloat16 bf16;
typedef __attribute__((ext_vector_type(8))) short bh8;
typedef __attribute__((ext_vector_type(4))) float f32x4;

__device__ __forceinline__ void gload16(const bf16* g, bf16* l) {
  __builtin_amdgcn_global_load_lds(
      (const __attribute__((address_space(1))) void*)g,
      (__attribute__((address_space(3))) void*)l, 16, 0, 0);
}

__device__ __forceinline__ void cstore(bf16* p, float v)  { *p = __float2bfloat16(v); }
__device__ __forceinline__ void cstore(float* p, float v) { *p = v; }

// fp32 -> bf16 elementwise (n multiple of 8)
__global__ __launch_bounds__(256) void cvt32to16(const float* __restrict__ src,
                                                 bf16* __restrict__ dst, int n)
{
  const int stride = gridDim.x * 256 * 8;
  for (int i = (blockIdx.x * 256 + threadIdx.x) * 8; i < n; i += stride) {
    const float4 a = *(const float4*)(src + i);
    const float4 b = *(const float4*)(src + i + 4);
    bf16 o[8];
    o[0]=__float2bfloat16(a.x); o[1]=__float2bfloat16(a.y);
    o[2]=__float2bfloat16(a.z); o[3]=__float2bfloat16(a.w);
    o[4]=__float2bfloat16(b.x); o[5]=__float2bfloat16(b.y);
    o[6]=__float2bfloat16(b.z); o[7]=__float2bfloat16(b.w);
    *(bh8*)(dst + i) = *(const bh8*)o;
  }
}

// C[m][n] = sum_k A[m][k] * Bmat[n][k];  A:[M][K] row-major, Bmat:[N][K] row-major.
// blockIdx.z selects (B0,C0) or (B1,C1) so K and V projections share one launch.
template<typename OutT>
__global__ __launch_bounds__(256) void gemm_bt(
    const bf16* __restrict__ A,
    const bf16* __restrict__ B0, const bf16* __restrict__ B1,
    OutT* __restrict__ C0, OutT* __restrict__ C1,
    int N, int K)
{
  const bf16* Bm = (blockIdx.z == 0) ? B0 : B1;
  OutT* Cm       = (blockIdx.z == 0) ? C0 : C1;
  const int n0 = blockIdx.x * 128;
  const int m0 = blockIdx.y * 128;
  const int tid  = threadIdx.x;
  const int lane = tid & 63;
  const int w    = tid >> 6;          // wave 0..3
  const int wr   = w >> 1, wc = w & 1; // 2x2 waves, 64x64 out each
  const int l15  = lane & 15;
  const int lk   = (lane >> 4) * 8;
  const int srow = lane >> 3;          // staging: 0..7
  const int scol = (lane & 7) * 8;     // staging: 0,8,..,56

  __shared__ bf16 As[128*64];
  __shared__ bf16 Bs[128*64];

  f32x4 acc[4][4] = {};

  for (int k0 = 0; k0 < K; k0 += 64) {
    #pragma unroll
    for (int i = 0; i < 4; ++i) {
      const int chunk = w*4 + i;            // 16 x 1KB chunks
      const int row   = chunk*8 + srow;     // 0..127
      gload16(A  + (size_t)(m0+row)*K + k0 + scol, &As[chunk*512 + lane*8]);
      gload16(Bm + (size_t)(n0+row)*K + k0 + scol, &Bs[chunk*512 + lane*8]);
    }
    __syncthreads();
    #pragma unroll
    for (int kk = 0; kk < 2; ++kk) {
      bh8 af[4], bfr[4];
      #pragma unroll
      for (int mi=0;mi<4;mi++) af[mi]  = *(const bh8*)&As[(wr*64 + mi*16 + l15)*64 + kk*32 + lk];
      #pragma unroll
      for (int nj=0;nj<4;nj++) bfr[nj] = *(const bh8*)&Bs[(wc*64 + nj*16 + l15)*64 + kk*32 + lk];
      #pragma unroll
      for (int mi=0;mi<4;mi++)
        #pragma unroll
        for (int nj=0;nj<4;nj++)
          acc[mi][nj] = __builtin_amdgcn_mfma_f32_16x16x32_bf16(af[mi], bfr[nj], acc[mi][nj], 0,0,0);
    }
    __syncthreads();
  }

  #pragma unroll
  for (int mi=0;mi<4;mi++)
    #pragma unroll
    for (int r=0;r<4;r++) {
      const int row = m0 + wr*64 + mi*16 + (lane>>4)*4 + r;
      #pragma unroll
      for (int nj=0;nj<4;nj++) {
        const int col = n0 + wc*64 + nj*16 + l15;
        cstore(&Cm[(size_t)row*N + col], acc[mi][nj][r]);
      }
    }
}

// Per (b,t): RMSNorm(HD) + RoPE IN PLACE on q (16 heads, layout [b*t][NH*HD])
// and k (4 heads, layout [b*t][NKV*HD]). Lane l owns d=l and d=l+64.
// Norm weights are fp32 (reference dtype).
__global__ __launch_bounds__(256) void postproc(
    bf16* __restrict__ q, bf16* __restrict__ k,
    const float* __restrict__ qw, const float* __restrict__ kw)
{
  const int blk  = blockIdx.x;          // b*T + t
  const int t    = blk & (T_-1);
  const int lane = threadIdx.x & 63;
  const int w    = threadIdx.x >> 6;    // 0..3

  // inv_freq = 10000^(-lane/64); angle = t * inv_freq
  const float inv = expf(-(float)lane * (9.210340371976184f / 64.f));
  const float ang = (float)t * inv;
  const float cw = cosf(ang), sw = sinf(ang);

  #pragma unroll
  for (int hi = 0; hi < 4; ++hi) {
    const int h = w + hi*4;
    bf16* row = q + (size_t)blk*(NH_*HD_) + h*HD_;
    float x1 = __bfloat162float(row[lane]);
    float x2 = __bfloat162float(row[lane+64]);
    float ss = x1*x1 + x2*x2;
    #pragma unroll
    for (int m = 1; m < 64; m <<= 1) ss += __shfl_xor(ss, m, 64);
    const float rs = rsqrtf(ss*(1.f/128.f) + 1e-6f);
    const float g1 = 1.f + qw[lane];
    const float g2 = 1.f + qw[lane+64];
    const float n1 = x1*rs*g1, n2 = x2*rs*g2;
    row[lane]    = __float2bfloat16(n1*cw - n2*sw);
    row[lane+64] = __float2bfloat16(n2*cw + n1*sw);
  }
  {
    const int h = w;                    // 4 kv heads
    bf16* row = k + (size_t)blk*(NKV_*HD_) + h*HD_;
    float x1 = __bfloat162float(row[lane]);
    float x2 = __bfloat162float(row[lane+64]);
    float ss = x1*x1 + x2*x2;
    #pragma unroll
    for (int m = 1; m < 64; m <<= 1) ss += __shfl_xor(ss, m, 64);
    const float rs = rsqrtf(ss*(1.f/128.f) + 1e-6f);
    const float g1 = 1.f + kw[lane];
    const float g2 = 1.f + kw[lane+64];
    const float n1 = x1*rs*g1, n2 = x2*rs*g2;
    row[lane]    = __float2bfloat16(n1*cw - n2*sw);
    row[lane+64] = __float2bfloat16(n2*cw + n1*sw);
  }
}

// v_raw [b*T+t][kvh*128+d]  ->  Vt [b][kvh][d][T]  (batched 2048x512 transpose)
__global__ __launch_bounds__(256) void vtrans(const bf16* __restrict__ vraw,
                                              bf16* __restrict__ Vt)
{
  __shared__ bf16 tile[64][65];
  const int t0 = blockIdx.x * 64;
  const int c0 = blockIdx.y * 64;
  const int b  = blockIdx.z;
  const int tx = threadIdx.x & 63;
  const int ty = threadIdx.x >> 6;
  const bf16* src = vraw + (size_t)b * T_ * (NKV_*HD_);
  bf16* dst       = Vt   + (size_t)b * (NKV_*HD_) * T_;
  #pragma unroll
  for (int i = 0; i < 16; ++i) {
    const int r = i*4 + ty;
    tile[r][tx] = src[(size_t)(t0 + r)*(NKV_*HD_) + c0 + tx];
  }
  __syncthreads();
  #pragma unroll
  for (int i = 0; i < 16; ++i) {
    const int r = i*4 + ty;
    dst[(size_t)(c0 + r)*T_ + t0 + tx] = tile[tx][r];
  }
}

// Flash attention, causal, GQA. Block = 64 q rows (4 waves x 16), KV tiles of 64.
// Q: [b*t][NH*HD] (normed+roped). K: [b*t][NKV*HD] (normed+roped). V: [b][kvh][d][t].
__global__ __launch_bounds__(256) void attn(
    const bf16* __restrict__ Q, const bf16* __restrict__ Kb,
    const bf16* __restrict__ Vt, bf16* __restrict__ att)
{
  const int qt  = blockIdx.x;     // q tile 0..31
  const int h   = blockIdx.y;     // 0..15
  const int b   = blockIdx.z;     // 0..1
  const int kvh = h >> 2;
  const int tid = threadIdx.x, lane = tid & 63, w = tid >> 6;
  const int l15 = lane & 15;
  const int lk  = (lane >> 4) * 8;
  const int lr4 = (lane >> 4) * 4;

  const bf16* Vbase = Vt + (size_t)(b*NKV_ + kvh) * HD_ * T_;

  const int q0   = qt*64 + w*16;
  const int qrow = q0 + lr4;            // this lane's C-row base (add r)

  bh8 aQ[4];
  #pragma unroll
  for (int kk = 0; kk < 4; ++kk)
    aQ[kk] = *(const bh8*)&Q[(size_t)(b*T_ + q0 + l15)*(NH_*HD_) + h*HD_ + kk*32 + lk];

  __shared__ bf16 Plds[4][16*64];
  bf16* pl = Plds[w];

  float mrow[4] = {-1e30f,-1e30f,-1e30f,-1e30f};
  float lrow[4] = {0.f,0.f,0.f,0.f};
  f32x4 acc[8] = {};

  for (int j = 0; j <= qt; ++j) {
    const int kv0 = j*64;
    f32x4 S[4] = {};
    #pragma unroll
    for (int jb = 0; jb < 4; ++jb) {
      const bf16* kb = Kb + (size_t)(b*T_ + kv0 + jb*16 + l15)*(NKV_*HD_) + kvh*HD_ + lk;
      #pragma unroll
      for (int kk = 0; kk < 4; ++kk) {
        const bh8 bK = *(const bh8*)(kb + kk*32);
        S[jb] = __builtin_amdgcn_mfma_f32_16x16x32_bf16(aQ[kk], bK, S[jb], 0,0,0);
      }
    }
    const bool diag = (j == qt);
    #pragma unroll
    for (int r = 0; r < 4; ++r) {
      float sv[4];
      float mx = -1e30f;
      #pragma unroll
      for (int jb = 0; jb < 4; ++jb) {
        float s = S[jb][r] * SCALE_;
        if (diag && (kv0 + jb*16 + l15) > (qrow + r)) s = -1e30f;
        sv[jb] = s;
        mx = fmaxf(mx, s);
      }
      mx = fmaxf(mx, __shfl_xor(mx, 1, 64));
      mx = fmaxf(mx, __shfl_xor(mx, 2, 64));
      mx = fmaxf(mx, __shfl_xor(mx, 4, 64));
      mx = fmaxf(mx, __shfl_xor(mx, 8, 64));
      const float mn = fmaxf(mrow[r], mx);
      const float al = __expf(mrow[r] - mn);
      mrow[r] = mn;
      float sum = 0.f;
      #pragma unroll
      for (int jb = 0; jb < 4; ++jb) { sv[jb] = __expf(sv[jb] - mn); sum += sv[jb]; }
      sum += __shfl_xor(sum, 1, 64);
      sum += __shfl_xor(sum, 2, 64);
      sum += __shfl_xor(sum, 4, 64);
      sum += __shfl_xor(sum, 8, 64);
      lrow[r] = lrow[r]*al + sum;
      #pragma unroll
      for (int jd = 0; jd < 8; ++jd) acc[jd][r] *= al;
      #pragma unroll
      for (int jb = 0; jb < 4; ++jb)
        pl[(lr4 + r)*64 + jb*16 + l15] = __float2bfloat16(sv[jb]);
    }
    __syncthreads();   // P writes visible before fragment reads

    bh8 pa[2];
    pa[0] = *(const bh8*)&pl[l15*64 + 0  + lk];
    pa[1] = *(const bh8*)&pl[l15*64 + 32 + lk];
    #pragma unroll
    for (int jd = 0; jd < 8; ++jd) {
      const bf16* vb = Vbase + (size_t)(jd*16 + l15)*T_ + kv0 + lk;
      const bh8 bV0 = *(const bh8*)(vb);
      const bh8 bV1 = *(const bh8*)(vb + 32);
      acc[jd] = __builtin_amdgcn_mfma_f32_16x16x32_bf16(pa[0], bV0, acc[jd], 0,0,0);
      acc[jd] = __builtin_amdgcn_mfma_f32_16x16x32_bf16(pa[1], bV1, acc[jd], 0,0,0);
    }
    __syncthreads();   // fragment reads done before next tile's P writes
  }

  #pragma unroll
  for (int r = 0; r < 4; ++r) {
    const float inv = 1.f / lrow[r];
    const int trow = qrow + r;
    bf16* orow = att + ((size_t)(b*T_ + trow))*(NH_*HD_) + h*HD_;
    #pragma unroll
    for (int jd = 0; jd < 8; ++jd)
      orow[jd*16 + l15] = __float2bfloat16(acc[jd][r] * inv);
  }
}

extern "C" void kernel_launch(void* const* d_in, const int* in_sizes, int n_in,
                              void* d_out, int out_size, void* d_ws, size_t ws_size,
                              hipStream_t stream) {
  // Inputs fp32; OUTPUT fp32 (reference dtype). bf16 internal compute.
  const float* x  = (const float*)d_in[0];
  const float* Wq = (const float*)d_in[1];
  const float* Wk = (const float*)d_in[2];
  const float* Wv = (const float*)d_in[3];
  const float* Wo = (const float*)d_in[4];
  const float* qw = (const float*)d_in[5];
  const float* kw = (const float*)d_in[6];
  float* out = (float*)d_out;

  // ws layout (48 MB): att reuses xb (x dead after QKV GEMMs).
  char* ws = (char*)d_ws;
  bf16* xb   = (bf16*)(ws);                  // [4096][2048] 16MB  (-> att later)
  bf16* Wqb  = (bf16*)(ws + (16u<<20));      // [2048][2048]  8MB
  bf16* Wkb  = (bf16*)(ws + (24u<<20));      // [512][2048]   2MB
  bf16* Wvb  = (bf16*)(ws + (26u<<20));      // [512][2048]   2MB
  bf16* Wob  = (bf16*)(ws + (28u<<20));      // [2048][2048]  8MB
  bf16* kbuf = (bf16*)(ws + (36u<<20));      // [4096][512]   4MB
  bf16* vraw = (bf16*)(ws + (40u<<20));      // [4096][512]   4MB
  bf16* Vt   = (bf16*)(ws + (44u<<20));      // [b][kvh][d][t] 4MB
  bf16* att  = xb;                           // 16MB, after x is dead
  bf16* qbuf = (bf16*)d_out;                 // Q scratch in d_out (dead before final write)

  // fp32 -> bf16 converts
  cvt32to16<<<dim3(2048), 256, 0, stream>>>(x,  xb,  M_*H_);
  cvt32to16<<<dim3(1024), 256, 0, stream>>>(Wq, Wqb, NH_*HD_*H_);
  cvt32to16<<<dim3(256),  256, 0, stream>>>(Wk, Wkb, NKV_*HD_*H_);
  cvt32to16<<<dim3(256),  256, 0, stream>>>(Wv, Wvb, NKV_*HD_*H_);
  cvt32to16<<<dim3(1024), 256, 0, stream>>>(Wo, Wob, H_*NH_*HD_);

  // QKV projections (Q into d_out-as-scratch, bf16)
  gemm_bt<bf16><<<dim3(16,32,1), 256, 0, stream>>>(xb, Wqb, Wqb, qbuf, qbuf, NH_*HD_, H_);
  gemm_bt<bf16><<<dim3(4, 32,2), 256, 0, stream>>>(xb, Wkb, Wvb, kbuf, vraw, NKV_*HD_, H_);
  // RMSNorm + RoPE in place
  postproc<<<dim3(M_), 256, 0, stream>>>(qbuf, kbuf, qw, kw);
  // V transpose to [b][kvh][d][T]
  vtrans<<<dim3(T_/64, (NKV_*HD_)/64, B_), 256, 0, stream>>>(vraw, Vt);
  // causal GQA flash attention (att overwrites xb — x is dead here)
  attn<<<dim3(T_/64, NH_, B_), 256, 0, stream>>>(qbuf, kbuf, Vt, att);
  // output projection -> fp32 d_out (overwrites Q scratch; att lives in ws)
  gemm_bt<float><<<dim3(16,32,1), 256, 0, stream>>>(att, Wob, Wob, out, out, H_, NH_*HD_);
}

// Round 6
// 411.332 us; speedup vs baseline: 1.6805x; 1.6805x over previous
//
#include <hip/hip_runtime.h>
#include <hip/hip_bf16.h>
#include <stdint.h>

#define B_   2
#define T_   2048
#define H_   2048
#define NH_  16
#define NKV_ 4
#define HD_  128
#define M_   (B_*T_)
#define SCALE_ 0.08838834764831845f

typedef __hip_bfloat16 bf16;
typedef __attribute__((ext_vector_type(8))) short bh8;
typedef __attribute__((ext_vector_type(4))) float f32x4;

__device__ __forceinline__ void gload16(const bf16* g, bf16* l) {
  __builtin_amdgcn_global_load_lds(
      (const __attribute__((address_space(1))) void*)g,
      (__attribute__((address_space(3))) void*)l, 16, 0, 0);
}

__device__ __forceinline__ void cstore(bf16* p, float v)  { *p = __float2bfloat16(v); }
__device__ __forceinline__ void cstore(float* p, float v) { *p = v; }

// fp32 -> bf16 elementwise (n multiple of 8)
__global__ __launch_bounds__(256) void cvt32to16(const float* __restrict__ src,
                                                 bf16* __restrict__ dst, int n)
{
  const int stride = gridDim.x * 256 * 8;
  for (int i = (blockIdx.x * 256 + threadIdx.x) * 8; i < n; i += stride) {
    const float4 a = *(const float4*)(src + i);
    const float4 b = *(const float4*)(src + i + 4);
    bf16 o[8];
    o[0]=__float2bfloat16(a.x); o[1]=__float2bfloat16(a.y);
    o[2]=__float2bfloat16(a.z); o[3]=__float2bfloat16(a.w);
    o[4]=__float2bfloat16(b.x); o[5]=__float2bfloat16(b.y);
    o[6]=__float2bfloat16(b.z); o[7]=__float2bfloat16(b.w);
    *(bh8*)(dst + i) = *(const bh8*)o;
  }
}

// C[m][n] = sum_k A[m][k] * Bmat[n][k];  A:[M][K] row-major, Bmat:[N][K] row-major.
template<typename OutT>
__global__ __launch_bounds__(256) void gemm_bt(
    const bf16* __restrict__ A,
    const bf16* __restrict__ B0, const bf16* __restrict__ B1,
    OutT* __restrict__ C0, OutT* __restrict__ C1,
    int N, int K)
{
  const bf16* Bm = (blockIdx.z == 0) ? B0 : B1;
  OutT* Cm       = (blockIdx.z == 0) ? C0 : C1;
  const int n0 = blockIdx.x * 128;
  const int m0 = blockIdx.y * 128;
  const int tid  = threadIdx.x;
  const int lane = tid & 63;
  const int w    = tid >> 6;
  const int wr   = w >> 1, wc = w & 1;
  const int l15  = lane & 15;
  const int lk   = (lane >> 4) * 8;
  const int srow = lane >> 3;
  const int scol = (lane & 7) * 8;

  __shared__ bf16 As[128*64];
  __shared__ bf16 Bs[128*64];

  f32x4 acc[4][4] = {};

  for (int k0 = 0; k0 < K; k0 += 64) {
    #pragma unroll
    for (int i = 0; i < 4; ++i) {
      const int chunk = w*4 + i;
      const int row   = chunk*8 + srow;
      gload16(A  + (size_t)(m0+row)*K + k0 + scol, &As[chunk*512 + lane*8]);
      gload16(Bm + (size_t)(n0+row)*K + k0 + scol, &Bs[chunk*512 + lane*8]);
    }
    __syncthreads();
    #pragma unroll
    for (int kk = 0; kk < 2; ++kk) {
      bh8 af[4], bfr[4];
      #pragma unroll
      for (int mi=0;mi<4;mi++) af[mi]  = *(const bh8*)&As[(wr*64 + mi*16 + l15)*64 + kk*32 + lk];
      #pragma unroll
      for (int nj=0;nj<4;nj++) bfr[nj] = *(const bh8*)&Bs[(wc*64 + nj*16 + l15)*64 + kk*32 + lk];
      #pragma unroll
      for (int mi=0;mi<4;mi++)
        #pragma unroll
        for (int nj=0;nj<4;nj++)
          acc[mi][nj] = __builtin_amdgcn_mfma_f32_16x16x32_bf16(af[mi], bfr[nj], acc[mi][nj], 0,0,0);
    }
    __syncthreads();
  }

  #pragma unroll
  for (int mi=0;mi<4;mi++)
    #pragma unroll
    for (int r=0;r<4;r++) {
      const int row = m0 + wr*64 + mi*16 + (lane>>4)*4 + r;
      #pragma unroll
      for (int nj=0;nj<4;nj++) {
        const int col = n0 + wc*64 + nj*16 + l15;
        cstore(&Cm[(size_t)row*N + col], acc[mi][nj][r]);
      }
    }
}

// Per (b,t): RMSNorm(HD) + RoPE IN PLACE. Lane l owns d=l and d=l+64.
__global__ __launch_bounds__(256) void postproc(
    bf16* __restrict__ q, bf16* __restrict__ k,
    const float* __restrict__ qw, const float* __restrict__ kw)
{
  const int blk  = blockIdx.x;
  const int t    = blk & (T_-1);
  const int lane = threadIdx.x & 63;
  const int w    = threadIdx.x >> 6;

  const float inv = expf(-(float)lane * (9.210340371976184f / 64.f));
  const float ang = (float)t * inv;
  const float cw = cosf(ang), sw = sinf(ang);

  #pragma unroll
  for (int hi = 0; hi < 4; ++hi) {
    const int h = w + hi*4;
    bf16* row = q + (size_t)blk*(NH_*HD_) + h*HD_;
    float x1 = __bfloat162float(row[lane]);
    float x2 = __bfloat162float(row[lane+64]);
    float ss = x1*x1 + x2*x2;
    #pragma unroll
    for (int m = 1; m < 64; m <<= 1) ss += __shfl_xor(ss, m, 64);
    const float rs = rsqrtf(ss*(1.f/128.f) + 1e-6f);
    const float n1 = x1*rs*(1.f + qw[lane]), n2 = x2*rs*(1.f + qw[lane+64]);
    row[lane]    = __float2bfloat16(n1*cw - n2*sw);
    row[lane+64] = __float2bfloat16(n2*cw + n1*sw);
  }
  {
    bf16* row = k + (size_t)blk*(NKV_*HD_) + w*HD_;
    float x1 = __bfloat162float(row[lane]);
    float x2 = __bfloat162float(row[lane+64]);
    float ss = x1*x1 + x2*x2;
    #pragma unroll
    for (int m = 1; m < 64; m <<= 1) ss += __shfl_xor(ss, m, 64);
    const float rs = rsqrtf(ss*(1.f/128.f) + 1e-6f);
    const float n1 = x1*rs*(1.f + kw[lane]), n2 = x2*rs*(1.f + kw[lane+64]);
    row[lane]    = __float2bfloat16(n1*cw - n2*sw);
    row[lane+64] = __float2bfloat16(n2*cw + n1*sw);
  }
}

// v_raw [b*T+t][kvh*128+d]  ->  Vt [b][kvh][d][T]
__global__ __launch_bounds__(256) void vtrans(const bf16* __restrict__ vraw,
                                              bf16* __restrict__ Vt)
{
  __shared__ bf16 tile[64][65];
  const int t0 = blockIdx.x * 64;
  const int c0 = blockIdx.y * 64;
  const int b  = blockIdx.z;
  const int tx = threadIdx.x & 63;
  const int ty = threadIdx.x >> 6;
  const bf16* src = vraw + (size_t)b * T_ * (NKV_*HD_);
  bf16* dst       = Vt   + (size_t)b * (NKV_*HD_) * T_;
  #pragma unroll
  for (int i = 0; i < 16; ++i) {
    const int r = i*4 + ty;
    tile[r][tx] = src[(size_t)(t0 + r)*(NKV_*HD_) + c0 + tx];
  }
  __syncthreads();
  #pragma unroll
  for (int i = 0; i < 16; ++i) {
    const int r = i*4 + ty;
    dst[(size_t)(c0 + r)*T_ + t0 + tx] = tile[tx][r];
  }
}

// Flash attention v2: causal, GQA, balanced slice pairs, no barriers.
// Each wave owns TWO 16-row q-slices: s1 = 4p+w and s2 = 127-s1 -> uniformly
// 33 KV-tiles of 64 per wave. V + K-backhalf loads issue at iteration top;
// K-fronthalf prefetched one tile ahead. P tile is wave-private (ping-pong).
__global__ __launch_bounds__(256, 2) void attn(
    const bf16* __restrict__ Q, const bf16* __restrict__ Kb,
    const bf16* __restrict__ Vt, bf16* __restrict__ att)
{
  const int p   = blockIdx.x;     // pair 0..15
  const int h   = blockIdx.y;     // 0..15
  const int b   = blockIdx.z;     // 0..1
  const int kvh = h >> 2;
  const int tid = threadIdx.x, lane = tid & 63, w = tid >> 6;
  const int l15 = lane & 15;
  const int lk  = (lane >> 4) * 8;
  const int lr4 = (lane >> 4) * 4;

  const bf16* Vbase = Vt + (size_t)(b*NKV_ + kvh) * HD_ * T_;
  const bf16* Krow0 = Kb + (size_t)b*T_*(NKV_*HD_) + kvh*HD_ + lk;  // + t*(NKV_*HD_)

  __shared__ bf16 Plds[4][2][16*64];

  #pragma unroll
  for (int half = 0; half < 2; ++half) {
    const int s  = half ? (127 - 4*p - w) : (4*p + w);
    const int nt = half ? (32 - p) : (p + 1);
    const int q0 = s * 16;
    const int qrow = q0 + lr4;

    bh8 aQ[4];
    #pragma unroll
    for (int kk = 0; kk < 4; ++kk)
      aQ[kk] = *(const bh8*)&Q[(size_t)(b*T_ + q0 + l15)*(NH_*HD_) + h*HD_ + kk*32 + lk];

    f32x4 acc[8] = {};
    float mrow[4] = {-1e30f,-1e30f,-1e30f,-1e30f};
    float lrow[4] = {0.f,0.f,0.f,0.f};

    // prefetch K front half (rows kv0+0..31) for tile 0
    bh8 kp[2][4];
    #pragma unroll
    for (int jb = 0; jb < 2; ++jb)
      #pragma unroll
      for (int kk = 0; kk < 4; ++kk)
        kp[jb][kk] = *(const bh8*)(Krow0 + (size_t)(jb*16 + l15)*(NKV_*HD_) + kk*32);

    for (int j = 0; j < nt; ++j) {
      const int kv0 = j*64;

      // issue V loads for this tile (consumed in PV, ~full tile later)
      bh8 v0[8], v1[8];
      #pragma unroll
      for (int jd = 0; jd < 8; ++jd) {
        const bf16* vb = Vbase + (size_t)(jd*16 + l15)*T_ + kv0 + lk;
        v0[jd] = *(const bh8*)(vb);
        v1[jd] = *(const bh8*)(vb + 32);
      }
      // K back half (rows kv0+32..63)
      bh8 kc[2][4];
      #pragma unroll
      for (int jb = 0; jb < 2; ++jb)
        #pragma unroll
        for (int kk = 0; kk < 4; ++kk)
          kc[jb][kk] = *(const bh8*)(Krow0 + (size_t)(kv0 + (2+jb)*16 + l15)*(NKV_*HD_) + kk*32);

      // QK^T
      f32x4 S[4] = {};
      #pragma unroll
      for (int kk = 0; kk < 4; ++kk) {
        S[0] = __builtin_amdgcn_mfma_f32_16x16x32_bf16(aQ[kk], kp[0][kk], S[0], 0,0,0);
        S[1] = __builtin_amdgcn_mfma_f32_16x16x32_bf16(aQ[kk], kp[1][kk], S[1], 0,0,0);
      }
      #pragma unroll
      for (int kk = 0; kk < 4; ++kk) {
        S[2] = __builtin_amdgcn_mfma_f32_16x16x32_bf16(aQ[kk], kc[0][kk], S[2], 0,0,0);
        S[3] = __builtin_amdgcn_mfma_f32_16x16x32_bf16(aQ[kk], kc[1][kk], S[3], 0,0,0);
      }

      // prefetch K front half for next tile
      if (j + 1 < nt) {
        #pragma unroll
        for (int jb = 0; jb < 2; ++jb)
          #pragma unroll
          for (int kk = 0; kk < 4; ++kk)
            kp[jb][kk] = *(const bh8*)(Krow0 + (size_t)(kv0 + 64 + jb*16 + l15)*(NKV_*HD_) + kk*32);
      }

      // online softmax (wave-local; reductions within 16-lane groups)
      const bool diag = (j == nt - 1);
      bf16* pl = Plds[w][j & 1];
      #pragma unroll
      for (int r = 0; r < 4; ++r) {
        float sv[4];
        float mx = -1e30f;
        #pragma unroll
        for (int jb = 0; jb < 4; ++jb) {
          float sc = S[jb][r] * SCALE_;
          if (diag && (kv0 + jb*16 + l15) > (qrow + r)) sc = -1e30f;
          sv[jb] = sc;
          mx = fmaxf(mx, sc);
        }
        mx = fmaxf(mx, __shfl_xor(mx, 1, 64));
        mx = fmaxf(mx, __shfl_xor(mx, 2, 64));
        mx = fmaxf(mx, __shfl_xor(mx, 4, 64));
        mx = fmaxf(mx, __shfl_xor(mx, 8, 64));
        const float mn = fmaxf(mrow[r], mx);
        const float al = __expf(mrow[r] - mn);
        mrow[r] = mn;
        float sum = 0.f;
        #pragma unroll
        for (int jb = 0; jb < 4; ++jb) { sv[jb] = __expf(sv[jb] - mn); sum += sv[jb]; }
        sum += __shfl_xor(sum, 1, 64);
        sum += __shfl_xor(sum, 2, 64);
        sum += __shfl_xor(sum, 4, 64);
        sum += __shfl_xor(sum, 8, 64);
        lrow[r] = lrow[r]*al + sum;
        #pragma unroll
        for (int jd = 0; jd < 8; ++jd) acc[jd][r] *= al;
        #pragma unroll
        for (int jb = 0; jb < 4; ++jb)
          pl[(lr4 + r)*64 + jb*16 + l15] = __float2bfloat16(sv[jb]);
      }
      // wave-local ds_write -> ds_read ordering (rule 18)
      asm volatile("s_waitcnt lgkmcnt(0)" ::: "memory");
      __builtin_amdgcn_sched_barrier(0);

      bh8 pa0 = *(const bh8*)&pl[l15*64 + 0  + lk];
      bh8 pa1 = *(const bh8*)&pl[l15*64 + 32 + lk];
      #pragma unroll
      for (int jd = 0; jd < 8; ++jd) {
        acc[jd] = __builtin_amdgcn_mfma_f32_16x16x32_bf16(pa0, v0[jd], acc[jd], 0,0,0);
        acc[jd] = __builtin_amdgcn_mfma_f32_16x16x32_bf16(pa1, v1[jd], acc[jd], 0,0,0);
      }
    }

    #pragma unroll
    for (int r = 0; r < 4; ++r) {
      const float inv = 1.f / lrow[r];
      bf16* orow = att + ((size_t)(b*T_ + qrow + r))*(NH_*HD_) + h*HD_;
      #pragma unroll
      for (int jd = 0; jd < 8; ++jd)
        orow[jd*16 + l15] = __float2bfloat16(acc[jd][r] * inv);
    }
  }
}

extern "C" void kernel_launch(void* const* d_in, const int* in_sizes, int n_in,
                              void* d_out, int out_size, void* d_ws, size_t ws_size,
                              hipStream_t stream) {
  const float* x  = (const float*)d_in[0];
  const float* Wq = (const float*)d_in[1];
  const float* Wk = (const float*)d_in[2];
  const float* Wv = (const float*)d_in[3];
  const float* Wo = (const float*)d_in[4];
  const float* qw = (const float*)d_in[5];
  const float* kw = (const float*)d_in[6];
  float* out = (float*)d_out;

  char* ws = (char*)d_ws;
  bf16* xb   = (bf16*)(ws);                  // [4096][2048] 16MB  (-> att later)
  bf16* Wqb  = (bf16*)(ws + (16u<<20));      // 8MB
  bf16* Wkb  = (bf16*)(ws + (24u<<20));      // 2MB
  bf16* Wvb  = (bf16*)(ws + (26u<<20));      // 2MB
  bf16* Wob  = (bf16*)(ws + (28u<<20));      // 8MB
  bf16* kbuf = (bf16*)(ws + (36u<<20));      // 4MB
  bf16* vraw = (bf16*)(ws + (40u<<20));      // 4MB
  bf16* Vt   = (bf16*)(ws + (44u<<20));      // 4MB
  bf16* att  = xb;
  bf16* qbuf = (bf16*)d_out;                 // Q scratch in d_out

  cvt32to16<<<dim3(2048), 256, 0, stream>>>(x,  xb,  M_*H_);
  cvt32to16<<<dim3(1024), 256, 0, stream>>>(Wq, Wqb, NH_*HD_*H_);
  cvt32to16<<<dim3(256),  256, 0, stream>>>(Wk, Wkb, NKV_*HD_*H_);
  cvt32to16<<<dim3(256),  256, 0, stream>>>(Wv, Wvb, NKV_*HD_*H_);
  cvt32to16<<<dim3(1024), 256, 0, stream>>>(Wo, Wob, H_*NH_*HD_);

  gemm_bt<bf16><<<dim3(16,32,1), 256, 0, stream>>>(xb, Wqb, Wqb, qbuf, qbuf, NH_*HD_, H_);
  gemm_bt<bf16><<<dim3(4, 32,2), 256, 0, stream>>>(xb, Wkb, Wvb, kbuf, vraw, NKV_*HD_, H_);
  postproc<<<dim3(M_), 256, 0, stream>>>(qbuf, kbuf, qw, kw);
  vtrans<<<dim3(T_/64, (NKV_*HD_)/64, B_), 256, 0, stream>>>(vraw, Vt);
  attn<<<dim3(16, NH_, B_), 256, 0, stream>>>(qbuf, kbuf, Vt, att);
  gemm_bt<float><<<dim3(16,32,1), 256, 0, stream>>>(att, Wob, Wob, out, out, H_, NH_*HD_);
}

// Round 7
// 410.240 us; speedup vs baseline: 1.6850x; 1.0027x over previous
//
#include <hip/hip_runtime.h>
#include <hip/hip_bf16.h>
#include <stdint.h>

#define B_   2
#define T_   2048
#define H_   2048
#define NH_  16
#define NKV_ 4
#define HD_  128
#define M_   (B_*T_)
#define SCALE_ 0.08838834764831845f

typedef __hip_bfloat16 bf16;
typedef __attribute__((ext_vector_type(8))) short bh8;
typedef __attribute__((ext_vector_type(4))) float f32x4;
typedef __attribute__((ext_vector_type(4))) unsigned short us4;

__device__ __forceinline__ void gload16(const bf16* g, bf16* l) {
  __builtin_amdgcn_global_load_lds(
      (const __attribute__((address_space(1))) void*)g,
      (__attribute__((address_space(3))) void*)l, 16, 0, 0);
}

__device__ __forceinline__ void cstore(bf16* p, float v)  { *p = __float2bfloat16(v); }
__device__ __forceinline__ void cstore(float* p, float v) { *p = v; }

// fp32 -> bf16 elementwise (n multiple of 8)
__global__ __launch_bounds__(256) void cvt32to16(const float* __restrict__ src,
                                                 bf16* __restrict__ dst, int n)
{
  const int stride = gridDim.x * 256 * 8;
  for (int i = (blockIdx.x * 256 + threadIdx.x) * 8; i < n; i += stride) {
    const float4 a = *(const float4*)(src + i);
    const float4 b = *(const float4*)(src + i + 4);
    bf16 o[8];
    o[0]=__float2bfloat16(a.x); o[1]=__float2bfloat16(a.y);
    o[2]=__float2bfloat16(a.z); o[3]=__float2bfloat16(a.w);
    o[4]=__float2bfloat16(b.x); o[5]=__float2bfloat16(b.y);
    o[6]=__float2bfloat16(b.z); o[7]=__float2bfloat16(b.w);
    *(bh8*)(dst + i) = *(const bh8*)o;
  }
}

// C[m][n] = sum_k A[m][k] * Bmat[n][k];  A:[M][K] row-major, Bmat:[N][K] row-major.
template<typename OutT>
__global__ __launch_bounds__(256) void gemm_bt(
    const bf16* __restrict__ A,
    const bf16* __restrict__ B0, const bf16* __restrict__ B1,
    OutT* __restrict__ C0, OutT* __restrict__ C1,
    int N, int K)
{
  const bf16* Bm = (blockIdx.z == 0) ? B0 : B1;
  OutT* Cm       = (blockIdx.z == 0) ? C0 : C1;
  const int n0 = blockIdx.x * 128;
  const int m0 = blockIdx.y * 128;
  const int tid  = threadIdx.x;
  const int lane = tid & 63;
  const int w    = tid >> 6;
  const int wr   = w >> 1, wc = w & 1;
  const int l15  = lane & 15;
  const int lk   = (lane >> 4) * 8;
  const int srow = lane >> 3;
  const int scol = (lane & 7) * 8;

  __shared__ bf16 As[128*64];
  __shared__ bf16 Bs[128*64];

  f32x4 acc[4][4] = {};

  for (int k0 = 0; k0 < K; k0 += 64) {
    #pragma unroll
    for (int i = 0; i < 4; ++i) {
      const int chunk = w*4 + i;
      const int row   = chunk*8 + srow;
      gload16(A  + (size_t)(m0+row)*K + k0 + scol, &As[chunk*512 + lane*8]);
      gload16(Bm + (size_t)(n0+row)*K + k0 + scol, &Bs[chunk*512 + lane*8]);
    }
    __syncthreads();
    #pragma unroll
    for (int kk = 0; kk < 2; ++kk) {
      bh8 af[4], bfr[4];
      #pragma unroll
      for (int mi=0;mi<4;mi++) af[mi]  = *(const bh8*)&As[(wr*64 + mi*16 + l15)*64 + kk*32 + lk];
      #pragma unroll
      for (int nj=0;nj<4;nj++) bfr[nj] = *(const bh8*)&Bs[(wc*64 + nj*16 + l15)*64 + kk*32 + lk];
      #pragma unroll
      for (int mi=0;mi<4;mi++)
        #pragma unroll
        for (int nj=0;nj<4;nj++)
          acc[mi][nj] = __builtin_amdgcn_mfma_f32_16x16x32_bf16(af[mi], bfr[nj], acc[mi][nj], 0,0,0);
    }
    __syncthreads();
  }

  #pragma unroll
  for (int mi=0;mi<4;mi++)
    #pragma unroll
    for (int r=0;r<4;r++) {
      const int row = m0 + wr*64 + mi*16 + (lane>>4)*4 + r;
      #pragma unroll
      for (int nj=0;nj<4;nj++) {
        const int col = n0 + wc*64 + nj*16 + l15;
        cstore(&Cm[(size_t)row*N + col], acc[mi][nj][r]);
      }
    }
}

// Per (b,t): RMSNorm(HD) + RoPE IN PLACE. Lane l owns d=l and d=l+64.
__global__ __launch_bounds__(256) void postproc(
    bf16* __restrict__ q, bf16* __restrict__ k,
    const float* __restrict__ qw, const float* __restrict__ kw)
{
  const int blk  = blockIdx.x;
  const int t    = blk & (T_-1);
  const int lane = threadIdx.x & 63;
  const int w    = threadIdx.x >> 6;

  const float inv = expf(-(float)lane * (9.210340371976184f / 64.f));
  const float ang = (float)t * inv;
  const float cw = cosf(ang), sw = sinf(ang);

  #pragma unroll
  for (int hi = 0; hi < 4; ++hi) {
    const int h = w + hi*4;
    bf16* row = q + (size_t)blk*(NH_*HD_) + h*HD_;
    float x1 = __bfloat162float(row[lane]);
    float x2 = __bfloat162float(row[lane+64]);
    float ss = x1*x1 + x2*x2;
    #pragma unroll
    for (int m = 1; m < 64; m <<= 1) ss += __shfl_xor(ss, m, 64);
    const float rs = rsqrtf(ss*(1.f/128.f) + 1e-6f);
    const float n1 = x1*rs*(1.f + qw[lane]), n2 = x2*rs*(1.f + qw[lane+64]);
    row[lane]    = __float2bfloat16(n1*cw - n2*sw);
    row[lane+64] = __float2bfloat16(n2*cw + n1*sw);
  }
  {
    bf16* row = k + (size_t)blk*(NKV_*HD_) + w*HD_;
    float x1 = __bfloat162float(row[lane]);
    float x2 = __bfloat162float(row[lane+64]);
    float ss = x1*x1 + x2*x2;
    #pragma unroll
    for (int m = 1; m < 64; m <<= 1) ss += __shfl_xor(ss, m, 64);
    const float rs = rsqrtf(ss*(1.f/128.f) + 1e-6f);
    const float n1 = x1*rs*(1.f + kw[lane]), n2 = x2*rs*(1.f + kw[lane+64]);
    row[lane]    = __float2bfloat16(n1*cw - n2*sw);
    row[lane+64] = __float2bfloat16(n2*cw + n1*sw);
  }
}

// v_raw [b*T+t][kvh*128+d]  ->  Vt [b][kvh][d][T]
__global__ __launch_bounds__(256) void vtrans(const bf16* __restrict__ vraw,
                                              bf16* __restrict__ Vt)
{
  __shared__ bf16 tile[64][65];
  const int t0 = blockIdx.x * 64;
  const int c0 = blockIdx.y * 64;
  const int b  = blockIdx.z;
  const int tx = threadIdx.x & 63;
  const int ty = threadIdx.x >> 6;
  const bf16* src = vraw + (size_t)b * T_ * (NKV_*HD_);
  bf16* dst       = Vt   + (size_t)b * (NKV_*HD_) * T_;
  #pragma unroll
  for (int i = 0; i < 16; ++i) {
    const int r = i*4 + ty;
    tile[r][tx] = src[(size_t)(t0 + r)*(NKV_*HD_) + c0 + tx];
  }
  __syncthreads();
  #pragma unroll
  for (int i = 0; i < 16; ++i) {
    const int r = i*4 + ty;
    dst[(size_t)(c0 + r)*T_ + t0 + tx] = tile[tx][r];
  }
}

// Flash attention v3: swapped-operand QK^T (S^T = K x Q) so each lane owns one
// q-row (q = lane&15) -> in-lane softmax, only 2 shfl hops per reduction.
// Balanced slice pairs (s, 127-s): uniformly 33 KV tiles per wave, no barriers.
__global__ __launch_bounds__(256, 2) void attn(
    const bf16* __restrict__ Q, const bf16* __restrict__ Kb,
    const bf16* __restrict__ Vt, bf16* __restrict__ att)
{
  const int p   = blockIdx.x;     // pair 0..15
  const int h   = blockIdx.y;     // 0..15
  const int b   = blockIdx.z;     // 0..1
  const int kvh = h >> 2;
  const int tid = threadIdx.x, lane = tid & 63, w = tid >> 6;
  const int l15 = lane & 15;
  const int g   = lane >> 4;      // 0..3
  const int lk  = g * 8;
  const int lr4 = g * 4;

  const bf16* Vbase = Vt + (size_t)(b*NKV_ + kvh) * HD_ * T_;
  const bf16* Krow0 = Kb + (size_t)b*T_*(NKV_*HD_) + kvh*HD_ + lk;

  // [wave][ping][q=16][kv stride 72] (72 = 16B-aligned rows, bank-spread)
  __shared__ bf16 Plds[4][2][16*72];

  #pragma unroll
  for (int half = 0; half < 2; ++half) {
    const int s  = half ? (127 - 4*p - w) : (4*p + w);
    const int nt = half ? (32 - p) : (p + 1);
    const int q0 = s * 16;

    bh8 aQ[4];
    #pragma unroll
    for (int kk = 0; kk < 4; ++kk)
      aQ[kk] = *(const bh8*)&Q[(size_t)(b*T_ + q0 + l15)*(NH_*HD_) + h*HD_ + kk*32 + lk];

    f32x4 acc[8] = {};
    float mL = -1e30f;   // running row max, q = q0 + l15 (replicated x4 groups)
    float lL = 0.f;      // running row sum

    // prefetch K rows [0,32) of tile 0
    bh8 kp[2][4];
    #pragma unroll
    for (int jb = 0; jb < 2; ++jb)
      #pragma unroll
      for (int kk = 0; kk < 4; ++kk)
        kp[jb][kk] = *(const bh8*)(Krow0 + (size_t)(jb*16 + l15)*(NKV_*HD_) + kk*32);

    for (int j = 0; j < nt; ++j) {
      const int kv0 = j*64;

      // K back half first (needed by S[2],S[3] soon)
      bh8 kc[2][4];
      #pragma unroll
      for (int jb = 0; jb < 2; ++jb)
        #pragma unroll
        for (int kk = 0; kk < 4; ++kk)
          kc[jb][kk] = *(const bh8*)(Krow0 + (size_t)(kv0 + (2+jb)*16 + l15)*(NKV_*HD_) + kk*32);
      // V loads (consumed at PV, end of iteration)
      bh8 v0[8], v1[8];
      #pragma unroll
      for (int jd = 0; jd < 8; ++jd) {
        const bf16* vb = Vbase + (size_t)(jd*16 + l15)*T_ + kv0 + lk;
        v0[jd] = *(const bh8*)(vb);
        v1[jd] = *(const bh8*)(vb + 32);
      }

      // swapped QK^T: S[jb] rows = kv (jb*16 + lr4 + r), cols = q (l15)
      f32x4 S[4] = {};
      #pragma unroll
      for (int kk = 0; kk < 4; ++kk) {
        S[0] = __builtin_amdgcn_mfma_f32_16x16x32_bf16(kp[0][kk], aQ[kk], S[0], 0,0,0);
        S[1] = __builtin_amdgcn_mfma_f32_16x16x32_bf16(kp[1][kk], aQ[kk], S[1], 0,0,0);
      }
      #pragma unroll
      for (int kk = 0; kk < 4; ++kk) {
        S[2] = __builtin_amdgcn_mfma_f32_16x16x32_bf16(kc[0][kk], aQ[kk], S[2], 0,0,0);
        S[3] = __builtin_amdgcn_mfma_f32_16x16x32_bf16(kc[1][kk], aQ[kk], S[3], 0,0,0);
      }

      // prefetch K front half of next tile
      if (j + 1 < nt) {
        #pragma unroll
        for (int jb = 0; jb < 2; ++jb)
          #pragma unroll
          for (int kk = 0; kk < 4; ++kk)
            kp[jb][kk] = *(const bh8*)(Krow0 + (size_t)(kv0 + 64 + jb*16 + l15)*(NKV_*HD_) + kk*32);
      }

      // in-lane softmax over this lane's 16 scores of row q = q0 + l15
      const bool diag = (j == nt - 1);
      float sv[16];
      float mx = -1e30f;
      #pragma unroll
      for (int jb = 0; jb < 4; ++jb)
        #pragma unroll
        for (int r = 0; r < 4; ++r) {
          float sc = S[jb][r] * SCALE_;
          if (diag && (kv0 + jb*16 + lr4 + r) > (q0 + l15)) sc = -1e30f;
          sv[jb*4+r] = sc;
          mx = fmaxf(mx, sc);
        }
      mx = fmaxf(mx, __shfl_xor(mx, 16, 64));
      mx = fmaxf(mx, __shfl_xor(mx, 32, 64));
      const float mn = fmaxf(mL, mx);
      const float al = __expf(mL - mn);
      mL = mn;
      float sum = 0.f;
      #pragma unroll
      for (int i = 0; i < 16; ++i) { sv[i] = __expf(sv[i] - mn); sum += sv[i]; }
      sum += __shfl_xor(sum, 16, 64);
      sum += __shfl_xor(sum, 32, 64);
      lL = lL*al + sum;

      // bring al into acc space (q = q0 + lr4 + r): src lane has l15 = lr4+r
      float alr[4];
      #pragma unroll
      for (int r = 0; r < 4; ++r)
        alr[r] = __shfl(al, (lane & 48) | (lr4 + r), 64);
      #pragma unroll
      for (int jd = 0; jd < 8; ++jd)
        #pragma unroll
        for (int r = 0; r < 4; ++r) acc[jd][r] *= alr[r];

      // P -> LDS (wave-private): row q=l15, cols kv; 4x ds_write_b64
      bf16* pl = Plds[w][j & 1];
      #pragma unroll
      for (int jb = 0; jb < 4; ++jb) {
        bf16 pk[4];
        #pragma unroll
        for (int r = 0; r < 4; ++r) pk[r] = __float2bfloat16(sv[jb*4+r]);
        *(us4*)(&pl[l15*72 + jb*16 + lr4]) = *(const us4*)pk;
      }
      asm volatile("s_waitcnt lgkmcnt(0)" ::: "memory");
      __builtin_amdgcn_sched_barrier(0);

      const bh8 pa0 = *(const bh8*)&pl[l15*72 + lk];
      const bh8 pa1 = *(const bh8*)&pl[l15*72 + 32 + lk];
      #pragma unroll
      for (int jd = 0; jd < 8; ++jd) {
        acc[jd] = __builtin_amdgcn_mfma_f32_16x16x32_bf16(pa0, v0[jd], acc[jd], 0,0,0);
        acc[jd] = __builtin_amdgcn_mfma_f32_16x16x32_bf16(pa1, v1[jd], acc[jd], 0,0,0);
      }
    }

    // output: bring 1/l into acc space
    float lar[4];
    #pragma unroll
    for (int r = 0; r < 4; ++r)
      lar[r] = __shfl(lL, (lane & 48) | (lr4 + r), 64);
    #pragma unroll
    for (int r = 0; r < 4; ++r) {
      const float inv = 1.f / lar[r];
      bf16* orow = att + ((size_t)(b*T_ + q0 + lr4 + r))*(NH_*HD_) + h*HD_;
      #pragma unroll
      for (int jd = 0; jd < 8; ++jd)
        orow[jd*16 + l15] = __float2bfloat16(acc[jd][r] * inv);
    }
  }
}

extern "C" void kernel_launch(void* const* d_in, const int* in_sizes, int n_in,
                              void* d_out, int out_size, void* d_ws, size_t ws_size,
                              hipStream_t stream) {
  const float* x  = (const float*)d_in[0];
  const float* Wq = (const float*)d_in[1];
  const float* Wk = (const float*)d_in[2];
  const float* Wv = (const float*)d_in[3];
  const float* Wo = (const float*)d_in[4];
  const float* qw = (const float*)d_in[5];
  const float* kw = (const float*)d_in[6];
  float* out = (float*)d_out;

  char* ws = (char*)d_ws;
  bf16* xb   = (bf16*)(ws);                  // 16MB  (-> att later)
  bf16* Wqb  = (bf16*)(ws + (16u<<20));      // 8MB
  bf16* Wkb  = (bf16*)(ws + (24u<<20));      // 2MB
  bf16* Wvb  = (bf16*)(ws + (26u<<20));      // 2MB
  bf16* Wob  = (bf16*)(ws + (28u<<20));      // 8MB
  bf16* kbuf = (bf16*)(ws + (36u<<20));      // 4MB
  bf16* vraw = (bf16*)(ws + (40u<<20));      // 4MB
  bf16* Vt   = (bf16*)(ws + (44u<<20));      // 4MB
  bf16* att  = xb;
  bf16* qbuf = (bf16*)d_out;                 // Q scratch in d_out

  cvt32to16<<<dim3(2048), 256, 0, stream>>>(x,  xb,  M_*H_);
  cvt32to16<<<dim3(1024), 256, 0, stream>>>(Wq, Wqb, NH_*HD_*H_);
  cvt32to16<<<dim3(256),  256, 0, stream>>>(Wk, Wkb, NKV_*HD_*H_);
  cvt32to16<<<dim3(256),  256, 0, stream>>>(Wv, Wvb, NKV_*HD_*H_);
  cvt32to16<<<dim3(1024), 256, 0, stream>>>(Wo, Wob, H_*NH_*HD_);

  gemm_bt<bf16><<<dim3(16,32,1), 256, 0, stream>>>(xb, Wqb, Wqb, qbuf, qbuf, NH_*HD_, H_);
  gemm_bt<bf16><<<dim3(4, 32,2), 256, 0, stream>>>(xb, Wkb, Wvb, kbuf, vraw, NKV_*HD_, H_);
  postproc<<<dim3(M_), 256, 0, stream>>>(qbuf, kbuf, qw, kw);
  vtrans<<<dim3(T_/64, (NKV_*HD_)/64, B_), 256, 0, stream>>>(vraw, Vt);
  attn<<<dim3(16, NH_, B_), 256, 0, stream>>>(qbuf, kbuf, Vt, att);
  gemm_bt<float><<<dim3(16,32,1), 256, 0, stream>>>(att, Wob, Wob, out, out, H_, NH_*HD_);
}

// Round 8
// 400.976 us; speedup vs baseline: 1.7239x; 1.0231x over previous
//
#include <hip/hip_runtime.h>
#include <hip/hip_bf16.h>
#include <stdint.h>

#define B_   2
#define T_   2048
#define H_   2048
#define NH_  16
#define NKV_ 4
#define HD_  128
#define M_   (B_*T_)
#define SCALE_ 0.08838834764831845f

typedef __hip_bfloat16 bf16;
typedef __attribute__((ext_vector_type(8))) short bh8;
typedef __attribute__((ext_vector_type(4))) float f32x4;
typedef __attribute__((ext_vector_type(4))) unsigned short us4;

__device__ __forceinline__ void gload16(const bf16* g, bf16* l) {
  __builtin_amdgcn_global_load_lds(
      (const __attribute__((address_space(1))) void*)g,
      (__attribute__((address_space(3))) void*)l, 16, 0, 0);
}

__device__ __forceinline__ void cstore(bf16* p, float v)  { *p = __float2bfloat16(v); }
__device__ __forceinline__ void cstore(float* p, float v) { *p = v; }

// fp32 -> bf16 elementwise (n multiple of 8)
__global__ __launch_bounds__(256) void cvt32to16(const float* __restrict__ src,
                                                 bf16* __restrict__ dst, int n)
{
  const int stride = gridDim.x * 256 * 8;
  for (int i = (blockIdx.x * 256 + threadIdx.x) * 8; i < n; i += stride) {
    const float4 a = *(const float4*)(src + i);
    const float4 b = *(const float4*)(src + i + 4);
    bf16 o[8];
    o[0]=__float2bfloat16(a.x); o[1]=__float2bfloat16(a.y);
    o[2]=__float2bfloat16(a.z); o[3]=__float2bfloat16(a.w);
    o[4]=__float2bfloat16(b.x); o[5]=__float2bfloat16(b.y);
    o[6]=__float2bfloat16(b.z); o[7]=__float2bfloat16(b.w);
    *(bh8*)(dst + i) = *(const bh8*)o;
  }
}

// C[m][n] = sum_k A[m][k] * Bmat[n][k];  A:[M][K] row-major, Bmat:[N][K] row-major.
template<typename OutT>
__global__ __launch_bounds__(256) void gemm_bt(
    const bf16* __restrict__ A,
    const bf16* __restrict__ B0, const bf16* __restrict__ B1,
    OutT* __restrict__ C0, OutT* __restrict__ C1,
    int N, int K)
{
  const bf16* Bm = (blockIdx.z == 0) ? B0 : B1;
  OutT* Cm       = (blockIdx.z == 0) ? C0 : C1;
  const int n0 = blockIdx.x * 128;
  const int m0 = blockIdx.y * 128;
  const int tid  = threadIdx.x;
  const int lane = tid & 63;
  const int w    = tid >> 6;
  const int wr   = w >> 1, wc = w & 1;
  const int l15  = lane & 15;
  const int lk   = (lane >> 4) * 8;
  const int srow = lane >> 3;
  const int scol = (lane & 7) * 8;

  __shared__ bf16 As[128*64];
  __shared__ bf16 Bs[128*64];

  f32x4 acc[4][4] = {};

  for (int k0 = 0; k0 < K; k0 += 64) {
    #pragma unroll
    for (int i = 0; i < 4; ++i) {
      const int chunk = w*4 + i;
      const int row   = chunk*8 + srow;
      gload16(A  + (size_t)(m0+row)*K + k0 + scol, &As[chunk*512 + lane*8]);
      gload16(Bm + (size_t)(n0+row)*K + k0 + scol, &Bs[chunk*512 + lane*8]);
    }
    __syncthreads();
    #pragma unroll
    for (int kk = 0; kk < 2; ++kk) {
      bh8 af[4], bfr[4];
      #pragma unroll
      for (int mi=0;mi<4;mi++) af[mi]  = *(const bh8*)&As[(wr*64 + mi*16 + l15)*64 + kk*32 + lk];
      #pragma unroll
      for (int nj=0;nj<4;nj++) bfr[nj] = *(const bh8*)&Bs[(wc*64 + nj*16 + l15)*64 + kk*32 + lk];
      #pragma unroll
      for (int mi=0;mi<4;mi++)
        #pragma unroll
        for (int nj=0;nj<4;nj++)
          acc[mi][nj] = __builtin_amdgcn_mfma_f32_16x16x32_bf16(af[mi], bfr[nj], acc[mi][nj], 0,0,0);
    }
    __syncthreads();
  }

  #pragma unroll
  for (int mi=0;mi<4;mi++)
    #pragma unroll
    for (int r=0;r<4;r++) {
      const int row = m0 + wr*64 + mi*16 + (lane>>4)*4 + r;
      #pragma unroll
      for (int nj=0;nj<4;nj++) {
        const int col = n0 + wc*64 + nj*16 + l15;
        cstore(&Cm[(size_t)row*N + col], acc[mi][nj][r]);
      }
    }
}

// Per (b,t): RMSNorm(HD) + RoPE IN PLACE. Lane l owns d=l and d=l+64.
__global__ __launch_bounds__(256) void postproc(
    bf16* __restrict__ q, bf16* __restrict__ k,
    const float* __restrict__ qw, const float* __restrict__ kw)
{
  const int blk  = blockIdx.x;
  const int t    = blk & (T_-1);
  const int lane = threadIdx.x & 63;
  const int w    = threadIdx.x >> 6;

  const float inv = expf(-(float)lane * (9.210340371976184f / 64.f));
  const float ang = (float)t * inv;
  const float cw = cosf(ang), sw = sinf(ang);

  #pragma unroll
  for (int hi = 0; hi < 4; ++hi) {
    const int h = w + hi*4;
    bf16* row = q + (size_t)blk*(NH_*HD_) + h*HD_;
    float x1 = __bfloat162float(row[lane]);
    float x2 = __bfloat162float(row[lane+64]);
    float ss = x1*x1 + x2*x2;
    #pragma unroll
    for (int m = 1; m < 64; m <<= 1) ss += __shfl_xor(ss, m, 64);
    const float rs = rsqrtf(ss*(1.f/128.f) + 1e-6f);
    const float n1 = x1*rs*(1.f + qw[lane]), n2 = x2*rs*(1.f + qw[lane+64]);
    row[lane]    = __float2bfloat16(n1*cw - n2*sw);
    row[lane+64] = __float2bfloat16(n2*cw + n1*sw);
  }
  {
    bf16* row = k + (size_t)blk*(NKV_*HD_) + w*HD_;
    float x1 = __bfloat162float(row[lane]);
    float x2 = __bfloat162float(row[lane+64]);
    float ss = x1*x1 + x2*x2;
    #pragma unroll
    for (int m = 1; m < 64; m <<= 1) ss += __shfl_xor(ss, m, 64);
    const float rs = rsqrtf(ss*(1.f/128.f) + 1e-6f);
    const float n1 = x1*rs*(1.f + kw[lane]), n2 = x2*rs*(1.f + kw[lane+64]);
    row[lane]    = __float2bfloat16(n1*cw - n2*sw);
    row[lane+64] = __float2bfloat16(n2*cw + n1*sw);
  }
}

// v_raw [b*T+t][kvh*128+d]  ->  Vt [b][kvh][d][T]
__global__ __launch_bounds__(256) void vtrans(const bf16* __restrict__ vraw,
                                              bf16* __restrict__ Vt)
{
  __shared__ bf16 tile[64][65];
  const int t0 = blockIdx.x * 64;
  const int c0 = blockIdx.y * 64;
  const int b  = blockIdx.z;
  const int tx = threadIdx.x & 63;
  const int ty = threadIdx.x >> 6;
  const bf16* src = vraw + (size_t)b * T_ * (NKV_*HD_);
  bf16* dst       = Vt   + (size_t)b * (NKV_*HD_) * T_;
  #pragma unroll
  for (int i = 0; i < 16; ++i) {
    const int r = i*4 + ty;
    tile[r][tx] = src[(size_t)(t0 + r)*(NKV_*HD_) + c0 + tx];
  }
  __syncthreads();
  #pragma unroll
  for (int i = 0; i < 16; ++i) {
    const int r = i*4 + ty;
    dst[(size_t)(c0 + r)*T_ + t0 + tx] = tile[tx][r];
  }
}

// Flash attention v5: swapped-operand QK^T, 32 q-rows per wave (2 x 16-row
// fragments share each K/V tile -> 2x arithmetic intensity per loaded byte).
// Fat-register schedule (~240 VGPR target, 2 waves/SIMD), loads issued early
// and kept in flight. Grid: wave-task S = 63-(4*bx+w), heavy-first dispatch.
__global__ __launch_bounds__(256, 2) void attn(
    const bf16* __restrict__ Q, const bf16* __restrict__ Kb,
    const bf16* __restrict__ Vt, bf16* __restrict__ att)
{
  const int h   = blockIdx.y;     // 0..15
  const int b   = blockIdx.z;     // 0..1
  const int kvh = h >> 2;
  const int tid = threadIdx.x, lane = tid & 63, w = tid >> 6;
  const int l15 = lane & 15;
  const int g   = lane >> 4;      // 0..3
  const int lk  = g * 8;
  const int lr4 = g * 4;

  const int S  = 63 - (blockIdx.x*4 + w);   // 32-row slice, heavy first
  const int nt = (S >> 1) + 1;              // KV tiles of 64
  const int q0 = S * 32;

  const bf16* Vbase = Vt + (size_t)(b*NKV_ + kvh) * HD_ * T_;
  const bf16* Krow0 = Kb + (size_t)b*T_*(NKV_*HD_) + kvh*HD_ + lk;
  const bf16* Qbase = Q  + (size_t)(b*T_)*(NH_*HD_) + h*HD_;

  // wave-private P tiles, ping-pong: [wave][pp][q=32][kv stride 72]
  __shared__ bf16 Plds[4][2][32*72];

  bh8 aQ[2][4];
  #pragma unroll
  for (int t = 0; t < 2; ++t)
    #pragma unroll
    for (int kk = 0; kk < 4; ++kk)
      aQ[t][kk] = *(const bh8*)&Qbase[(size_t)(q0 + t*16 + l15)*(NH_*HD_) + kk*32 + lk];

  f32x4 acc[2][8] = {};
  float mL[2] = {-1e30f, -1e30f};
  float lL[2] = {0.f, 0.f};

  for (int j = 0; j < nt; ++j) {
    const int kv0 = j*64;

    // issue K quarters a (kv 0..31)
    bh8 ka[2][4];
    #pragma unroll
    for (int jb = 0; jb < 2; ++jb)
      #pragma unroll
      for (int kk = 0; kk < 4; ++kk)
        ka[jb][kk] = *(const bh8*)(Krow0 + (size_t)(kv0 + jb*16 + l15)*(NKV_*HD_) + kk*32);
    // issue V first half (kv 0..31)
    bh8 v0[8];
    #pragma unroll
    for (int jd = 0; jd < 8; ++jd)
      v0[jd] = *(const bh8*)(Vbase + (size_t)(jd*16 + l15)*T_ + kv0 + lk);
    // issue K quarters b (kv 32..63)
    bh8 kb2[2][4];
    #pragma unroll
    for (int jb = 0; jb < 2; ++jb)
      #pragma unroll
      for (int kk = 0; kk < 4; ++kk)
        kb2[jb][kk] = *(const bh8*)(Krow0 + (size_t)(kv0 + 32 + jb*16 + l15)*(NKV_*HD_) + kk*32);

    // QK^T on first K half (S^T: rows = kv, cols = q)
    f32x4 Sx[4][2] = {};
    #pragma unroll
    for (int kk = 0; kk < 4; ++kk)
      #pragma unroll
      for (int t = 0; t < 2; ++t) {
        Sx[0][t] = __builtin_amdgcn_mfma_f32_16x16x32_bf16(ka[0][kk], aQ[t][kk], Sx[0][t], 0,0,0);
        Sx[1][t] = __builtin_amdgcn_mfma_f32_16x16x32_bf16(ka[1][kk], aQ[t][kk], Sx[1][t], 0,0,0);
      }
    // issue V second half (kv 32..63)
    bh8 v1[8];
    #pragma unroll
    for (int jd = 0; jd < 8; ++jd)
      v1[jd] = *(const bh8*)(Vbase + (size_t)(jd*16 + l15)*T_ + kv0 + 32 + lk);
    // QK^T on second K half
    #pragma unroll
    for (int kk = 0; kk < 4; ++kk)
      #pragma unroll
      for (int t = 0; t < 2; ++t) {
        Sx[2][t] = __builtin_amdgcn_mfma_f32_16x16x32_bf16(kb2[0][kk], aQ[t][kk], Sx[2][t], 0,0,0);
        Sx[3][t] = __builtin_amdgcn_mfma_f32_16x16x32_bf16(kb2[1][kk], aQ[t][kk], Sx[3][t], 0,0,0);
      }

    // in-lane online softmax per q-half; lane owns row q = q0 + t*16 + l15
    const bool diag = (j == nt - 1);
    bf16* pl = Plds[w][j & 1];
    float al[2];
    #pragma unroll
    for (int t = 0; t < 2; ++t) {
      float sv[16];
      float mx = -1e30f;
      #pragma unroll
      for (int jb = 0; jb < 4; ++jb)
        #pragma unroll
        for (int r = 0; r < 4; ++r) {
          float sc = Sx[jb][t][r] * SCALE_;
          if (diag && (kv0 + jb*16 + lr4 + r) > (q0 + t*16 + l15)) sc = -1e30f;
          sv[jb*4+r] = sc;
          mx = fmaxf(mx, sc);
        }
      mx = fmaxf(mx, __shfl_xor(mx, 16, 64));
      mx = fmaxf(mx, __shfl_xor(mx, 32, 64));
      const float mn = fmaxf(mL[t], mx);
      al[t] = __expf(mL[t] - mn);
      mL[t] = mn;
      float sum = 0.f;
      #pragma unroll
      for (int i = 0; i < 16; ++i) { sv[i] = __expf(sv[i] - mn); sum += sv[i]; }
      sum += __shfl_xor(sum, 16, 64);
      sum += __shfl_xor(sum, 32, 64);
      lL[t] = lL[t]*al[t] + sum;
      // P rows for this half: row = t*16 + l15, cols kv
      #pragma unroll
      for (int jb = 0; jb < 4; ++jb) {
        bf16 pk[4];
        #pragma unroll
        for (int r = 0; r < 4; ++r) pk[r] = __float2bfloat16(sv[jb*4+r]);
        *(us4*)(&pl[(t*16 + l15)*72 + jb*16 + lr4]) = *(const us4*)pk;
      }
    }

    // rescale acc by al brought into acc row-space (q = q0 + t*16 + lr4 + r)
    float alr[2][4];
    #pragma unroll
    for (int t = 0; t < 2; ++t)
      #pragma unroll
      for (int r = 0; r < 4; ++r)
        alr[t][r] = __shfl(al[t], (lane & 48) | (lr4 + r), 64);
    #pragma unroll
    for (int t = 0; t < 2; ++t)
      #pragma unroll
      for (int jd = 0; jd < 8; ++jd)
        #pragma unroll
        for (int r = 0; r < 4; ++r) acc[t][jd][r] *= alr[t][r];

    // wave-local ds_write -> ds_read ordering (rule 18)
    asm volatile("s_waitcnt lgkmcnt(0)" ::: "memory");
    __builtin_amdgcn_sched_barrier(0);

    bh8 pa[2][2];
    #pragma unroll
    for (int t = 0; t < 2; ++t) {
      pa[t][0] = *(const bh8*)&pl[(t*16 + l15)*72 + lk];
      pa[t][1] = *(const bh8*)&pl[(t*16 + l15)*72 + 32 + lk];
    }
    #pragma unroll
    for (int t = 0; t < 2; ++t)
      #pragma unroll
      for (int jd = 0; jd < 8; ++jd) {
        acc[t][jd] = __builtin_amdgcn_mfma_f32_16x16x32_bf16(pa[t][0], v0[jd], acc[t][jd], 0,0,0);
        acc[t][jd] = __builtin_amdgcn_mfma_f32_16x16x32_bf16(pa[t][1], v1[jd], acc[t][jd], 0,0,0);
      }
  }

  // epilogue: bring 1/l into acc row-space and store
  float lar[2][4];
  #pragma unroll
  for (int t = 0; t < 2; ++t)
    #pragma unroll
    for (int r = 0; r < 4; ++r)
      lar[t][r] = __shfl(lL[t], (lane & 48) | (lr4 + r), 64);
  #pragma unroll
  for (int t = 0; t < 2; ++t)
    #pragma unroll
    for (int r = 0; r < 4; ++r) {
      const float inv = 1.f / lar[t][r];
      const int row = q0 + t*16 + lr4 + r;
      bf16* orow = att + ((size_t)(b*T_ + row))*(NH_*HD_) + h*HD_;
      #pragma unroll
      for (int jd = 0; jd < 8; ++jd)
        orow[jd*16 + l15] = __float2bfloat16(acc[t][jd][r] * inv);
    }
}

extern "C" void kernel_launch(void* const* d_in, const int* in_sizes, int n_in,
                              void* d_out, int out_size, void* d_ws, size_t ws_size,
                              hipStream_t stream) {
  const float* x  = (const float*)d_in[0];
  const float* Wq = (const float*)d_in[1];
  const float* Wk = (const float*)d_in[2];
  const float* Wv = (const float*)d_in[3];
  const float* Wo = (const float*)d_in[4];
  const float* qw = (const float*)d_in[5];
  const float* kw = (const float*)d_in[6];
  float* out = (float*)d_out;

  char* ws = (char*)d_ws;
  bf16* xb   = (bf16*)(ws);                  // 16MB  (-> att later)
  bf16* Wqb  = (bf16*)(ws + (16u<<20));      // 8MB
  bf16* Wkb  = (bf16*)(ws + (24u<<20));      // 2MB
  bf16* Wvb  = (bf16*)(ws + (26u<<20));      // 2MB
  bf16* Wob  = (bf16*)(ws + (28u<<20));      // 8MB
  bf16* kbuf = (bf16*)(ws + (36u<<20));      // 4MB
  bf16* vraw = (bf16*)(ws + (40u<<20));      // 4MB
  bf16* Vt   = (bf16*)(ws + (44u<<20));      // 4MB
  bf16* att  = xb;
  bf16* qbuf = (bf16*)d_out;                 // Q scratch in d_out

  cvt32to16<<<dim3(2048), 256, 0, stream>>>(x,  xb,  M_*H_);
  cvt32to16<<<dim3(1024), 256, 0, stream>>>(Wq, Wqb, NH_*HD_*H_);
  cvt32to16<<<dim3(256),  256, 0, stream>>>(Wk, Wkb, NKV_*HD_*H_);
  cvt32to16<<<dim3(256),  256, 0, stream>>>(Wv, Wvb, NKV_*HD_*H_);
  cvt32to16<<<dim3(1024), 256, 0, stream>>>(Wo, Wob, H_*NH_*HD_);

  gemm_bt<bf16><<<dim3(16,32,1), 256, 0, stream>>>(xb, Wqb, Wqb, qbuf, qbuf, NH_*HD_, H_);
  gemm_bt<bf16><<<dim3(4, 32,2), 256, 0, stream>>>(xb, Wkb, Wvb, kbuf, vraw, NKV_*HD_, H_);
  postproc<<<dim3(M_), 256, 0, stream>>>(qbuf, kbuf, qw, kw);
  vtrans<<<dim3(T_/64, (NKV_*HD_)/64, B_), 256, 0, stream>>>(vraw, Vt);
  attn<<<dim3(16, NH_, B_), 256, 0, stream>>>(qbuf, kbuf, Vt, att);
  gemm_bt<float><<<dim3(16,32,1), 256, 0, stream>>>(att, Wob, Wob, out, out, H_, NH_*HD_);
}

// Round 9
// 304.376 us; speedup vs baseline: 2.2710x; 1.3174x over previous
//
#include <hip/hip_runtime.h>
#include <hip/hip_bf16.h>
#include <stdint.h>

#define B_   2
#define T_   2048
#define H_   2048
#define NH_  16
#define NKV_ 4
#define HD_  128
#define M_   (B_*T_)
#define SCALE_ 0.08838834764831845f

typedef __hip_bfloat16 bf16;
typedef __attribute__((ext_vector_type(8))) short bh8;
typedef __attribute__((ext_vector_type(4))) float f32x4;
typedef __attribute__((ext_vector_type(4))) unsigned short us4;

__device__ __forceinline__ void gload16(const bf16* g, bf16* l) {
  __builtin_amdgcn_global_load_lds(
      (const __attribute__((address_space(1))) void*)g,
      (__attribute__((address_space(3))) void*)l, 16, 0, 0);
}

__device__ __forceinline__ void cstore(bf16* p, float v)  { *p = __float2bfloat16(v); }
__device__ __forceinline__ void cstore(float* p, float v) { *p = v; }

// fp32 -> bf16 elementwise (n multiple of 8)
__global__ __launch_bounds__(256) void cvt32to16(const float* __restrict__ src,
                                                 bf16* __restrict__ dst, int n)
{
  const int stride = gridDim.x * 256 * 8;
  for (int i = (blockIdx.x * 256 + threadIdx.x) * 8; i < n; i += stride) {
    const float4 a = *(const float4*)(src + i);
    const float4 b = *(const float4*)(src + i + 4);
    bf16 o[8];
    o[0]=__float2bfloat16(a.x); o[1]=__float2bfloat16(a.y);
    o[2]=__float2bfloat16(a.z); o[3]=__float2bfloat16(a.w);
    o[4]=__float2bfloat16(b.x); o[5]=__float2bfloat16(b.y);
    o[6]=__float2bfloat16(b.z); o[7]=__float2bfloat16(b.w);
    *(bh8*)(dst + i) = *(const bh8*)o;
  }
}

// C[m][n] = sum_k A[m][k] * Bmat[n][k];  A:[M][K] row-major, Bmat:[N][K] row-major.
template<typename OutT>
__global__ __launch_bounds__(256) void gemm_bt(
    const bf16* __restrict__ A,
    const bf16* __restrict__ B0, const bf16* __restrict__ B1,
    OutT* __restrict__ C0, OutT* __restrict__ C1,
    int N, int K)
{
  const bf16* Bm = (blockIdx.z == 0) ? B0 : B1;
  OutT* Cm       = (blockIdx.z == 0) ? C0 : C1;
  const int n0 = blockIdx.x * 128;
  const int m0 = blockIdx.y * 128;
  const int tid  = threadIdx.x;
  const int lane = tid & 63;
  const int w    = tid >> 6;
  const int wr   = w >> 1, wc = w & 1;
  const int l15  = lane & 15;
  const int lk   = (lane >> 4) * 8;
  const int srow = lane >> 3;
  const int scol = (lane & 7) * 8;

  __shared__ bf16 As[128*64];
  __shared__ bf16 Bs[128*64];

  f32x4 acc[4][4] = {};

  for (int k0 = 0; k0 < K; k0 += 64) {
    #pragma unroll
    for (int i = 0; i < 4; ++i) {
      const int chunk = w*4 + i;
      const int row   = chunk*8 + srow;
      gload16(A  + (size_t)(m0+row)*K + k0 + scol, &As[chunk*512 + lane*8]);
      gload16(Bm + (size_t)(n0+row)*K + k0 + scol, &Bs[chunk*512 + lane*8]);
    }
    __syncthreads();
    #pragma unroll
    for (int kk = 0; kk < 2; ++kk) {
      bh8 af[4], bfr[4];
      #pragma unroll
      for (int mi=0;mi<4;mi++) af[mi]  = *(const bh8*)&As[(wr*64 + mi*16 + l15)*64 + kk*32 + lk];
      #pragma unroll
      for (int nj=0;nj<4;nj++) bfr[nj] = *(const bh8*)&Bs[(wc*64 + nj*16 + l15)*64 + kk*32 + lk];
      #pragma unroll
      for (int mi=0;mi<4;mi++)
        #pragma unroll
        for (int nj=0;nj<4;nj++)
          acc[mi][nj] = __builtin_amdgcn_mfma_f32_16x16x32_bf16(af[mi], bfr[nj], acc[mi][nj], 0,0,0);
    }
    __syncthreads();
  }

  #pragma unroll
  for (int mi=0;mi<4;mi++)
    #pragma unroll
    for (int r=0;r<4;r++) {
      const int row = m0 + wr*64 + mi*16 + (lane>>4)*4 + r;
      #pragma unroll
      for (int nj=0;nj<4;nj++) {
        const int col = n0 + wc*64 + nj*16 + l15;
        cstore(&Cm[(size_t)row*N + col], acc[mi][nj][r]);
      }
    }
}

// Per (b,t): RMSNorm(HD) + RoPE IN PLACE. Lane l owns d=l and d=l+64.
__global__ __launch_bounds__(256) void postproc(
    bf16* __restrict__ q, bf16* __restrict__ k,
    const float* __restrict__ qw, const float* __restrict__ kw)
{
  const int blk  = blockIdx.x;
  const int t    = blk & (T_-1);
  const int lane = threadIdx.x & 63;
  const int w    = threadIdx.x >> 6;

  const float inv = expf(-(float)lane * (9.210340371976184f / 64.f));
  const float ang = (float)t * inv;
  const float cw = cosf(ang), sw = sinf(ang);

  #pragma unroll
  for (int hi = 0; hi < 4; ++hi) {
    const int h = w + hi*4;
    bf16* row = q + (size_t)blk*(NH_*HD_) + h*HD_;
    float x1 = __bfloat162float(row[lane]);
    float x2 = __bfloat162float(row[lane+64]);
    float ss = x1*x1 + x2*x2;
    #pragma unroll
    for (int m = 1; m < 64; m <<= 1) ss += __shfl_xor(ss, m, 64);
    const float rs = rsqrtf(ss*(1.f/128.f) + 1e-6f);
    const float n1 = x1*rs*(1.f + qw[lane]), n2 = x2*rs*(1.f + qw[lane+64]);
    row[lane]    = __float2bfloat16(n1*cw - n2*sw);
    row[lane+64] = __float2bfloat16(n2*cw + n1*sw);
  }
  {
    bf16* row = k + (size_t)blk*(NKV_*HD_) + w*HD_;
    float x1 = __bfloat162float(row[lane]);
    float x2 = __bfloat162float(row[lane+64]);
    float ss = x1*x1 + x2*x2;
    #pragma unroll
    for (int m = 1; m < 64; m <<= 1) ss += __shfl_xor(ss, m, 64);
    const float rs = rsqrtf(ss*(1.f/128.f) + 1e-6f);
    const float n1 = x1*rs*(1.f + kw[lane]), n2 = x2*rs*(1.f + kw[lane+64]);
    row[lane]    = __float2bfloat16(n1*cw - n2*sw);
    row[lane+64] = __float2bfloat16(n2*cw + n1*sw);
  }
}

// v_raw [b*T+t][kvh*128+d]  ->  Vt [b][kvh][d][T]
__global__ __launch_bounds__(256) void vtrans(const bf16* __restrict__ vraw,
                                              bf16* __restrict__ Vt)
{
  __shared__ bf16 tile[64][65];
  const int t0 = blockIdx.x * 64;
  const int c0 = blockIdx.y * 64;
  const int b  = blockIdx.z;
  const int tx = threadIdx.x & 63;
  const int ty = threadIdx.x >> 6;
  const bf16* src = vraw + (size_t)b * T_ * (NKV_*HD_);
  bf16* dst       = Vt   + (size_t)b * (NKV_*HD_) * T_;
  #pragma unroll
  for (int i = 0; i < 16; ++i) {
    const int r = i*4 + ty;
    tile[r][tx] = src[(size_t)(t0 + r)*(NKV_*HD_) + c0 + tx];
  }
  __syncthreads();
  #pragma unroll
  for (int i = 0; i < 16; ++i) {
    const int r = i*4 + ty;
    dst[(size_t)(c0 + r)*T_ + t0 + tx] = tile[tx][r];
  }
}

// Flash attention v6: block = one 64-row q-tile, 4 waves x 16 rows, K/V tiles
// cooperatively staged into LDS via global_load_lds (zero VGPR cost for the
// stream). LDS linear + XOR-swizzled source/read slots (rule 21). Swapped
// QK^T (in-lane softmax), P via wave-private LDS round-trip. Heavy-first grid.
__global__ __launch_bounds__(256, 3) void attn(
    const bf16* __restrict__ Q, const bf16* __restrict__ Kb,
    const bf16* __restrict__ Vt, bf16* __restrict__ att)
{
  const int qt  = 31 - blockIdx.x;     // heavy-first
  const int h   = blockIdx.y;          // 0..15
  const int b   = blockIdx.z;          // 0..1
  const int kvh = h >> 2;
  const int tid = threadIdx.x, lane = tid & 63, w = tid >> 6;
  const int l15 = lane & 15;
  const int g   = lane >> 4;           // 0..3
  const int lr4 = g * 4;
  const int swz = l15 & 7;             // read-side swizzle selector

  const int q0w = qt*64 + w*16;        // this wave's q base
  const int nt  = qt + 1;              // KV tiles of 64

  __shared__ bf16 Ks[64*128];          // [kv][d], 256B rows, swizzled slots
  __shared__ bf16 Vs[128*64];          // [d][kv], 128B rows, swizzled slots
  __shared__ bf16 Plds[4][2][16*72];   // wave-private P, ping-pong

  const bf16* Kglob = Kb + (size_t)b*T_*(NKV_*HD_) + kvh*HD_;
  const bf16* Vglob = Vt + (size_t)(b*NKV_ + kvh)*HD_*T_;

  // Q B-frag: col = l15 -> q = q0w + l15; k-elems at d = kk*32 + g*8 + j
  bh8 aQ[4];
  #pragma unroll
  for (int kk = 0; kk < 4; ++kk)
    aQ[kk] = *(const bh8*)&Q[(size_t)(b*T_ + q0w + l15)*(NH_*HD_) + h*HD_ + kk*32 + g*8];

  f32x4 acc[8] = {};
  float mL = -1e30f, lL = 0.f;

  for (int j = 0; j < nt; ++j) {
    const int kv0 = j*64;

    // stage K tile: 1024 chunks of 16B; chunk o -> row r = o>>4, slot s = o&15;
    // source slot pre-swizzled s ^ (r&7)  (LDS stays linear)
    #pragma unroll
    for (int i = 0; i < 4; ++i) {
      const int o = (w*4 + i)*64 + lane;
      const int r = o >> 4, s = o & 15;
      gload16(Kglob + (size_t)(kv0 + r)*(NKV_*HD_) + ((s ^ (r & 7)) << 3),
              &Ks[(w*4 + i)*512 + lane*8]);
    }
    // stage V tile: chunk o -> row d = o>>3, slot s2 = o&7; source slot s2 ^ (d&7)
    #pragma unroll
    for (int i = 0; i < 4; ++i) {
      const int o = (w*4 + i)*64 + lane;
      const int d = o >> 3, s2 = o & 7;
      gload16(Vglob + (size_t)d*T_ + kv0 + ((s2 ^ (d & 7)) << 3),
              &Vs[(w*4 + i)*512 + lane*8]);
    }
    asm volatile("s_waitcnt vmcnt(0)" ::: "memory");
    __syncthreads();

    // QK^T (swapped): S[jb] rows = kv(jb*16+lr4+r), cols = q(l15)
    f32x4 S[4] = {};
    #pragma unroll
    for (int jb = 0; jb < 4; ++jb)
      #pragma unroll
      for (int kk = 0; kk < 4; ++kk) {
        const bh8 kf = *(const bh8*)&Ks[(jb*16 + l15)*128 + (((kk*4 + g) ^ swz) << 3)];
        S[jb] = __builtin_amdgcn_mfma_f32_16x16x32_bf16(kf, aQ[kk], S[jb], 0,0,0);
      }

    // in-lane online softmax: lane owns q-row = q0w + l15 (16 scores)
    const bool diag = (j == nt - 1);
    float sv[16];
    float mx = -1e30f;
    #pragma unroll
    for (int jb = 0; jb < 4; ++jb)
      #pragma unroll
      for (int r = 0; r < 4; ++r) {
        float sc = S[jb][r] * SCALE_;
        if (diag && (kv0 + jb*16 + lr4 + r) > (q0w + l15)) sc = -1e30f;
        sv[jb*4 + r] = sc;
        mx = fmaxf(mx, sc);
      }
    mx = fmaxf(mx, __shfl_xor(mx, 16, 64));
    mx = fmaxf(mx, __shfl_xor(mx, 32, 64));
    const float mn = fmaxf(mL, mx);
    const float al = __expf(mL - mn);
    mL = mn;
    float sum = 0.f;
    #pragma unroll
    for (int i = 0; i < 16; ++i) { sv[i] = __expf(sv[i] - mn); sum += sv[i]; }
    sum += __shfl_xor(sum, 16, 64);
    sum += __shfl_xor(sum, 32, 64);
    lL = lL*al + sum;

    // P -> wave-private LDS (row q = l15, col kv)
    bf16* pl = Plds[w][j & 1];
    #pragma unroll
    for (int jb = 0; jb < 4; ++jb) {
      bf16 pk[4];
      #pragma unroll
      for (int r = 0; r < 4; ++r) pk[r] = __float2bfloat16(sv[jb*4 + r]);
      *(us4*)(&pl[l15*72 + jb*16 + lr4]) = *(const us4*)pk;
    }

    // rescale acc (acc rows q = q0w + lr4 + r): al from lane with l15 = lr4+r
    float alr[4];
    #pragma unroll
    for (int r = 0; r < 4; ++r)
      alr[r] = __shfl(al, (lane & 48) | (lr4 + r), 64);
    #pragma unroll
    for (int jd = 0; jd < 8; ++jd)
      #pragma unroll
      for (int r = 0; r < 4; ++r) acc[jd][r] *= alr[r];

    // wave-local ds_write -> ds_read ordering (rule 18)
    asm volatile("s_waitcnt lgkmcnt(0)" ::: "memory");
    __builtin_amdgcn_sched_barrier(0);

    const bh8 pa0 = *(const bh8*)&pl[l15*72 + g*8];
    const bh8 pa1 = *(const bh8*)&pl[l15*72 + 32 + g*8];
    #pragma unroll
    for (int jd = 0; jd < 8; ++jd) {
      const bh8 vf0 = *(const bh8*)&Vs[(jd*16 + l15)*64 + ((( g     ) ^ swz) << 3)];
      const bh8 vf1 = *(const bh8*)&Vs[(jd*16 + l15)*64 + (((4 + g  ) ^ swz) << 3)];
      acc[jd] = __builtin_amdgcn_mfma_f32_16x16x32_bf16(pa0, vf0, acc[jd], 0,0,0);
      acc[jd] = __builtin_amdgcn_mfma_f32_16x16x32_bf16(pa1, vf1, acc[jd], 0,0,0);
    }
    __syncthreads();   // all waves done with Ks/Vs before next staging
  }

  // epilogue: bring 1/l into acc row-space and store
  float lar[4];
  #pragma unroll
  for (int r = 0; r < 4; ++r)
    lar[r] = __shfl(lL, (lane & 48) | (lr4 + r), 64);
  #pragma unroll
  for (int r = 0; r < 4; ++r) {
    const float inv = 1.f / lar[r];
    const int row = q0w + lr4 + r;
    bf16* orow = att + ((size_t)(b*T_ + row))*(NH_*HD_) + h*HD_;
    #pragma unroll
    for (int jd = 0; jd < 8; ++jd)
      orow[jd*16 + l15] = __float2bfloat16(acc[jd][r] * inv);
  }
}

extern "C" void kernel_launch(void* const* d_in, const int* in_sizes, int n_in,
                              void* d_out, int out_size, void* d_ws, size_t ws_size,
                              hipStream_t stream) {
  const float* x  = (const float*)d_in[0];
  const float* Wq = (const float*)d_in[1];
  const float* Wk = (const float*)d_in[2];
  const float* Wv = (const float*)d_in[3];
  const float* Wo = (const float*)d_in[4];
  const float* qw = (const float*)d_in[5];
  const float* kw = (const float*)d_in[6];
  float* out = (float*)d_out;

  char* ws = (char*)d_ws;
  bf16* xb   = (bf16*)(ws);                  // 16MB  (-> att later)
  bf16* Wqb  = (bf16*)(ws + (16u<<20));      // 8MB
  bf16* Wkb  = (bf16*)(ws + (24u<<20));      // 2MB
  bf16* Wvb  = (bf16*)(ws + (26u<<20));      // 2MB
  bf16* Wob  = (bf16*)(ws + (28u<<20));      // 8MB
  bf16* kbuf = (bf16*)(ws + (36u<<20));      // 4MB
  bf16* vraw = (bf16*)(ws + (40u<<20));      // 4MB
  bf16* Vt   = (bf16*)(ws + (44u<<20));      // 4MB
  bf16* att  = xb;
  bf16* qbuf = (bf16*)d_out;                 // Q scratch in d_out

  cvt32to16<<<dim3(2048), 256, 0, stream>>>(x,  xb,  M_*H_);
  cvt32to16<<<dim3(1024), 256, 0, stream>>>(Wq, Wqb, NH_*HD_*H_);
  cvt32to16<<<dim3(256),  256, 0, stream>>>(Wk, Wkb, NKV_*HD_*H_);
  cvt32to16<<<dim3(256),  256, 0, stream>>>(Wv, Wvb, NKV_*HD_*H_);
  cvt32to16<<<dim3(1024), 256, 0, stream>>>(Wo, Wob, H_*NH_*HD_);

  gemm_bt<bf16><<<dim3(16,32,1), 256, 0, stream>>>(xb, Wqb, Wqb, qbuf, qbuf, NH_*HD_, H_);
  gemm_bt<bf16><<<dim3(4, 32,2), 256, 0, stream>>>(xb, Wkb, Wvb, kbuf, vraw, NKV_*HD_, H_);
  postproc<<<dim3(M_), 256, 0, stream>>>(qbuf, kbuf, qw, kw);
  vtrans<<<dim3(T_/64, (NKV_*HD_)/64, B_), 256, 0, stream>>>(vraw, Vt);
  attn<<<dim3(32, NH_, B_), 256, 0, stream>>>(qbuf, kbuf, Vt, att);
  gemm_bt<float><<<dim3(16,32,1), 256, 0, stream>>>(att, Wob, Wob, out, out, H_, NH_*HD_);
}